// Round 1
// baseline (821.464 us; speedup 1.0000x reference)
//
#include <hip/hip_runtime.h>
#include <math.h>

// Problem constants (fixed by setup_inputs)
#define NB 8
#define NC 128
#define NR 8
#define NT 24
#define SIG2 1.0001f

// workspace layout (float offsets). Total ~2.36 MB.
#define OFF_KFC   0
#define OFF_KFF   576
#define OFF_U     1152
#define OFF_S     1728
#define OFF_KU    1752
#define OFF_BT    2328
#define OFF_DVEC  18712
#define OFF_VD    21784
#define OFF_INVM  46360
#define OFF_W     47896
#define OFF_J     72472
#define OFF_N     97048
#define OFF_Y     490264
#define OFF_Z     514840
#define OFF_H2    539416
#define OFF_LOCP  563992

__device__ __forceinline__ float fsignf(float a, float b){ return copysignf(fabsf(a), b); }

__device__ float slapy2f(float x, float y){
  float xa=fabsf(x), ya=fabsf(y);
  float w=fmaxf(xa,ya), z=fminf(xa,ya);
  if (z==0.f) return w;
  float t=z/w;
  return w*sqrtf(1.f+t*t);
}

// LAPACK >=3.10 slartg (single). Pre-3.10 differs in sign convention; toggle next round if mean mismatches.
__device__ void slartgf(float f, float g, float& c, float& s, float& r){
  const float safmin=1.17549435e-38f;
  const float safmax=1.f/1.17549435e-38f;
  float f1=fabsf(f), g1=fabsf(g);
  if (g==0.f){ c=1.f; s=0.f; r=f; }
  else if (f==0.f){ c=0.f; s=copysignf(1.f,g); r=g1; }
  else {
    float rtmin=sqrtf(safmin);
    float rtmax=sqrtf(safmax*0.5f);
    if (f1>rtmin && f1<rtmax && g1>rtmin && g1<rtmax){
      float d=sqrtf(f*f+g*g);
      c=f1/d;
      r=copysignf(d,f);
      s=g/r;
    } else {
      float u=fminf(safmax, fmaxf(safmin, fmaxf(f1,g1)));
      float fs=f/u, gs=g/u;
      float d=sqrtf(fs*fs+gs*gs);
      c=fabsf(fs)/d;
      r=copysignf(d,f);
      s=gs/r;
      r=r*u;
    }
  }
}

__device__ void slaev2f(float a, float b, float c, float& rt1, float& rt2, float& cs1, float& sn1){
  float sm=a+c, df=a-c, adf=fabsf(df), tb=b+b, ab=fabsf(tb);
  float acmx, acmn;
  if (fabsf(a)>fabsf(c)){acmx=a;acmn=c;} else {acmx=c;acmn=a;}
  float rt;
  if (adf>ab){ float t=ab/adf; rt=adf*sqrtf(1.f+t*t); }
  else if (adf<ab){ float t=adf/ab; rt=ab*sqrtf(1.f+t*t); }
  else rt=ab*sqrtf(2.f);
  int sgn1;
  if (sm<0.f){ rt1=0.5f*(sm-rt); sgn1=-1; rt2=(acmx/rt1)*acmn-(b/rt1)*b; }
  else if (sm>0.f){ rt1=0.5f*(sm+rt); sgn1=1; rt2=(acmx/rt1)*acmn-(b/rt1)*b; }
  else { rt1=0.5f*rt; rt2=-0.5f*rt; sgn1=1; }
  float cs; int sgn2;
  if (df>=0.f){ cs=df+rt; sgn2=1; } else { cs=df-rt; sgn2=-1; }
  float acs=fabsf(cs);
  if (acs>ab){ float ct=-tb/cs; sn1=1.f/sqrtf(1.f+ct*ct); cs1=ct*sn1; }
  else {
    if (ab==0.f){ cs1=1.f; sn1=0.f; }
    else { float tn=-cs/tb; cs1=1.f/sqrtf(1.f+tn*tn); sn1=tn*cs1; }
  }
  if (sgn1==sgn2){ float tn=cs1; cs1=-sn1; sn1=tn; }
}

// K1: eigh(Kc) via faithful LAPACK ssyevd path (ssytd2 lower + ssteqr 'I' + sorm2r + sort).
// Single block, 64 threads; t0 runs scalar control (state machine), lanes apply Z updates.
__global__ __launch_bounds__(64) void k1_eigh(float* __restrict__ ws){
  __shared__ float A[24][24], Zs[24][24], Kf[24][24];
  __shared__ float dd[24], ee[24], tauv[24], wcA[24], wsA[24], wtmp[24];
  __shared__ int st_phase, st_l, st_lend, st_lsv, st_lendsv, st_l1, st_jtot, st_iscale, st_ii;
  __shared__ float st_anorm;
  __shared__ int s_cmd, s_p1, s_p2;
  const int tid = threadIdx.x;
  const float h = (float)(3.14159265358979323846/24.0);
  for (int idx=tid; idx<576; idx+=64){
    int i=idx/24, j=idx%24;
    float ti=(float)i*h, tj=(float)j*h, tf=(float)(24+i)*h, tg=(float)(24+j)*h;
    A[i][j]=expf(-fabsf(ti-tj));
    float kfc=expf(-fabsf(tf-tj));
    Kf[i][j]=kfc;
    ws[OFF_KFC+idx]=kfc;
    ws[OFF_KFF+idx]=expf(-fabsf(tf-tg));
  }
  __syncthreads();
  // ---------- ssytd2 (lower) ----------
  for (int i0=0;i0<23;i0++){
    if (tid==0){
      float alpha=A[i0+1][i0];
      float scale=0.f, ssq=1.f;
      for (int r=i0+2;r<24;r++){
        float ax=fabsf(A[r][i0]);
        if (ax!=0.f){
          if (scale<ax){ float t=scale/ax; ssq=1.f+ssq*t*t; scale=ax; }
          else { float t=ax/scale; ssq+=t*t; }
        }
      }
      float xnorm=scale*sqrtf(ssq);
      float taui, beta;
      if (xnorm==0.f){ taui=0.f; beta=alpha; }
      else {
        beta=-fsignf(slapy2f(alpha,xnorm), alpha);
        taui=(beta-alpha)/beta;
        float sc=1.f/(alpha-beta);
        for (int r=i0+2;r<24;r++) A[r][i0]*=sc;
      }
      ee[i0]=beta; tauv[i0]=taui;
      A[i0+1][i0]=1.f;
    }
    __syncthreads();
    float taui=tauv[i0];
    if (taui!=0.f){
      int m=23-i0;
      int j=i0+1+tid;
      if (tid<m){
        float acc=0.f;
        for (int k=i0+1;k<=j;k++) acc+=A[j][k]*A[k][i0];
        for (int k=j+1;k<24;k++)  acc+=A[k][j]*A[k][i0];
        wtmp[tid]=taui*acc;
      }
      __syncthreads();
      if (tid==0){
        float dt=0.f;
        for (int r=0;r<m;r++) dt+=wtmp[r]*A[i0+1+r][i0];
        float al=-0.5f*taui*dt;
        for (int r=0;r<m;r++) wtmp[r]+=al*A[i0+1+r][i0];
      }
      __syncthreads();
      if (tid<m){
        float vj=A[j][i0], wj=wtmp[tid];
        for (int k=i0+1;k<=j;k++) A[j][k]-=vj*wtmp[k-(i0+1)]+wj*A[k][i0];
      }
      __syncthreads();
    }
    if (tid==0){ A[i0+1][i0]=ee[i0]; dd[i0]=A[i0][i0]; }
    __syncthreads();
  }
  if (tid==0) dd[23]=A[23][23];
  for (int idx=tid; idx<576; idx+=64) Zs[idx/24][idx%24]=(idx/24==idx%24)?1.f:0.f;
  if (tid==0){ st_phase=0; st_l=1; st_lend=1; st_lsv=1; st_lendsv=1; st_l1=1; st_jtot=0; st_iscale=0; st_ii=2; st_anorm=0.f; }
  __syncthreads();
  // ---------- ssteqr('I') state machine ----------
  const float LEPS=5.9604645e-08f, EPS2=LEPS*LEPS, SAFMIN=1.17549435e-38f;
  const float SSFMAX=sqrtf(1.f/SAFMIN)/3.f, SSFMIN=sqrtf(SAFMIN)/EPS2;
  const int NMAXIT=720;
  #define D1(i) dd[(i)-1]
  #define E1(i) ee[(i)-1]
  #define WC1(i) wcA[(i)-1]
  #define WS1(i) wsA[(i)-1]
  for (int guard=0; guard<30000; ++guard){
    if (tid==0){
      int phase=st_phase,l=st_l,lend=st_lend,lsv=st_lsv,lendsv=st_lendsv,l1=st_l1,jtot=st_jtot,iscale=st_iscale,ii=st_ii;
      float anorm=st_anorm;
      int cmd=0,p1=1,p2=2;
      int iguard=0;
      while (cmd==0){
        if (++iguard>100000){ cmd=4; break; }
        if (phase==0){ // outer block search (label 10/30)
          if (l1>24){ phase=4; continue; }
          if (l1>1) E1(l1-1)=0.f;
          int m=24;
          for (int mm=l1; mm<=23; mm++){
            float tst=fabsf(E1(mm));
            if (tst==0.f){ m=mm; break; }
            if (tst<=(sqrtf(fabsf(D1(mm)))*sqrtf(fabsf(D1(mm+1))))*LEPS){ E1(mm)=0.f; m=mm; break; }
          }
          l=l1; lsv=l; lend=m; lendsv=m; l1=m+1;
          if (lend==l) continue;
          anorm=0.f;
          for (int i=l;i<=lend;i++) anorm=fmaxf(anorm,fabsf(D1(i)));
          for (int i=l;i<=lend-1;i++) anorm=fmaxf(anorm,fabsf(E1(i)));
          iscale=0;
          if (anorm==0.f) continue;
          if (anorm>SSFMAX){ iscale=1; float sc=SSFMAX/anorm; for (int i=l;i<=lend;i++) D1(i)*=sc; for (int i=l;i<lend;i++) E1(i)*=sc; }
          else if (anorm<SSFMIN){ iscale=2; float sc=SSFMIN/anorm; for (int i=l;i<=lend;i++) D1(i)*=sc; for (int i=l;i<lend;i++) E1(i)*=sc; }
          if (fabsf(D1(lend))<fabsf(D1(l))){ lend=lsv; l=lendsv; }
          phase=(lend>l)?1:2;
          continue;
        }
        if (phase==1){ // QL (label 40)
          int m=lend;
          if (l!=lend){
            for (int mm=l;mm<=lend-1;mm++){
              float tst=fabsf(E1(mm)); tst*=tst;
              if (tst<=(EPS2*fabsf(D1(mm)))*fabsf(D1(mm+1))+SAFMIN){ m=mm; break; }
            }
          }
          if (m<lend) E1(m)=0.f;
          float p=D1(l);
          if (m==l){ D1(l)=p; l=l+1; if (l>lend) phase=3; continue; }
          if (m==l+1){
            float rt1,rt2,cc,ssv;
            slaev2f(D1(l),E1(l),D1(l+1),rt1,rt2,cc,ssv);
            WC1(l)=cc; WS1(l)=ssv;
            D1(l)=rt1; D1(l+1)=rt2; E1(l)=0.f;
            cmd=1; p1=l; p2=2;
            l=l+2;
            if (l>lend) phase=3;
            continue;
          }
          if (jtot==NMAXIT){ phase=3; continue; }
          jtot++;
          float g=(D1(l+1)-p)/(2.f*E1(l));
          float r=slapy2f(g,1.f);
          g=D1(m)-p+(E1(l)/(g+fsignf(r,g)));
          float sv=1.f, cv=1.f;
          p=0.f;
          for (int i=m-1;i>=l;i--){
            float fv=sv*E1(i), bv=cv*E1(i);
            slartgf(g,fv,cv,sv,r);
            if (i!=m-1) E1(i+1)=r;
            g=D1(i+1)-p;
            r=(D1(i)-g)*sv+2.f*cv*bv;
            p=sv*r;
            D1(i+1)=g+p;
            g=cv*r-bv;
            WC1(i)=cv; WS1(i)=-sv;
          }
          D1(l)=D1(l)-p;
          E1(l)=g;
          cmd=1; p1=l; p2=m-l+1;
          continue;
        }
        if (phase==2){ // QR (label 90)
          int m=lend;
          if (l!=lend){
            for (int mm=l;mm>=lend+1;mm--){
              float tst=fabsf(E1(mm-1)); tst*=tst;
              if (tst<=(EPS2*fabsf(D1(mm)))*fabsf(D1(mm-1))+SAFMIN){ m=mm; break; }
            }
          }
          if (m>lend) E1(m-1)=0.f;
          float p=D1(l);
          if (m==l){ D1(l)=p; l=l-1; if (l<lend) phase=3; continue; }
          if (m==l-1){
            float rt1,rt2,cc,ssv;
            slaev2f(D1(l-1),E1(l-1),D1(l),rt1,rt2,cc,ssv);
            WC1(m)=cc; WS1(m)=ssv;
            D1(l-1)=rt1; D1(l)=rt2; E1(l-1)=0.f;
            cmd=2; p1=m; p2=2;
            l=l-2;
            if (l<lend) phase=3;
            continue;
          }
          if (jtot==NMAXIT){ phase=3; continue; }
          jtot++;
          float g=(D1(l-1)-p)/(2.f*E1(l-1));
          float r=slapy2f(g,1.f);
          g=D1(m)-p+(E1(l-1)/(g+fsignf(r,g)));
          float sv=1.f, cv=1.f;
          p=0.f;
          for (int i=m;i<=l-1;i++){
            float fv=sv*E1(i), bv=cv*E1(i);
            slartgf(g,fv,cv,sv,r);
            if (i!=m) E1(i-1)=r;
            g=D1(i)-p;
            r=(D1(i+1)-g)*sv+2.f*cv*bv;
            p=sv*r;
            D1(i)=g+p;
            g=cv*r-bv;
            WC1(i)=cv; WS1(i)=sv;
          }
          D1(l)=D1(l)-p;
          E1(l-1)=g;
          cmd=2; p1=m; p2=l-m+1;
          continue;
        }
        if (phase==3){ // label 140: undo scaling, next block
          if (iscale==1){ float sc=anorm/SSFMAX; for (int i=lsv;i<=lendsv;i++) D1(i)*=sc; for (int i=lsv;i<lendsv;i++) E1(i)*=sc; }
          else if (iscale==2){ float sc=anorm/SSFMIN; for (int i=lsv;i<=lendsv;i++) D1(i)*=sc; for (int i=lsv;i<lendsv;i++) E1(i)*=sc; }
          phase=(jtot<NMAXIT)?0:4;
          continue;
        }
        { // phase 4: ascending selection sort with column swaps
          if (ii>24){ cmd=4; continue; }
          int i=ii-1, k=i; float p=D1(i);
          for (int jq=ii;jq<=24;jq++) if (D1(jq)<p){ k=jq; p=D1(jq); }
          ii++;
          if (k!=i){ D1(k)=D1(i); D1(i)=p; cmd=3; p1=i; p2=k; }
          continue;
        }
      }
      st_phase=phase; st_l=l; st_lend=lend; st_lsv=lsv; st_lendsv=lendsv; st_l1=l1; st_jtot=jtot; st_iscale=iscale; st_ii=ii; st_anorm=anorm;
      s_cmd=cmd; s_p1=p1; s_p2=p2;
    }
    __syncthreads();
    int cmd=s_cmd;
    if (tid<24){
      if (cmd==1){ // slasr 'R','V','B'
        for (int j=s_p1+s_p2-2;j>=s_p1;j--){
          float ct=WC1(j), stv=WS1(j);
          if (ct!=1.f || stv!=0.f){
            float zb=Zs[tid][j], za=Zs[tid][j-1];
            Zs[tid][j]  =ct*zb-stv*za;
            Zs[tid][j-1]=stv*zb+ct*za;
          }
        }
      } else if (cmd==2){ // slasr 'R','V','F'
        for (int j=s_p1;j<=s_p1+s_p2-2;j++){
          float ct=WC1(j), stv=WS1(j);
          if (ct!=1.f || stv!=0.f){
            float zb=Zs[tid][j], za=Zs[tid][j-1];
            Zs[tid][j]  =ct*zb-stv*za;
            Zs[tid][j-1]=stv*zb+ct*za;
          }
        }
      } else if (cmd==3){
        float t=Zs[tid][s_p1-1]; Zs[tid][s_p1-1]=Zs[tid][s_p2-1]; Zs[tid][s_p2-1]=t;
      }
    }
    __syncthreads();
    if (s_cmd==4) break;
  }
  // ---------- sorm2r: evec = Q * Z  (H(k)..H(1) applied, lane = column) ----------
  if (tid<24){
    int jc=tid;
    for (int i0=22;i0>=0;i0--){
      float taui=tauv[i0];
      if (taui!=0.f){
        float wv=Zs[i0+1][jc];
        for (int r=i0+2;r<24;r++) wv+=A[r][i0]*Zs[r][jc];
        Zs[i0+1][jc]-=taui*wv;
        for (int r=i0+2;r<24;r++) Zs[r][jc]-=taui*A[r][i0]*wv;
      }
    }
  }
  __syncthreads();
  for (int idx=tid; idx<576; idx+=64) ws[OFF_U+idx]=Zs[idx/24][idx%24];
  if (tid<24) ws[OFF_S+tid]=dd[tid];
  __syncthreads();
  for (int idx=tid; idx<576; idx+=64){
    int f=idx/24, lq=idx%24;
    float acc=0.f;
    for (int i=0;i<24;i++) acc+=Kf[f][i]*Zs[i][lq];
    ws[OFF_KU+idx]=acc;
  }
  #undef D1
  #undef E1
  #undef WC1
  #undef WS1
}

// K0: Bt = V V^T + diag(tv)
__global__ __launch_bounds__(256) void k0_bt(const float* __restrict__ V, const float* __restrict__ tv, float* __restrict__ ws){
  int idx=blockIdx.x*256+threadIdx.x;
  int c=idx>>7, d=idx&127;
  float acc=0.f;
  for (int r=0;r<8;r++) acc+=V[c*8+r]*V[d*8+r];
  if (c==d) acc+=tv[c];
  ws[OFF_BT+idx]=acc;
}

// K4: Y[b][l][c] and loc_phase[b][c][f]
__global__ __launch_bounds__(256) void k4_y(const float* __restrict__ x, float* __restrict__ ws){
  int idx=blockIdx.x*256+threadIdx.x; // 24576
  int b=idx/3072, r2=idx%3072, i=r2/128, j=r2&127;
  const float* xb=x+(size_t)(b*128+j)*48;
  ws[OFF_Y + b*3072 + i*128 + j] = xb[24+i]-0.5f*(xb[12+(i>>1)]+xb[36+(i>>1)]);
  ws[OFF_LOCP + (b*128+j)*24 + i] = 0.5f*(xb[i]+xb[24+i]);
}

// K2: per time-mode Woodbury factors: dvec, Vd, invM, W=Bt*Vd, J=W*invM
__global__ __launch_bounds__(128) void k2_wood(const float* __restrict__ V, const float* __restrict__ tv, float* __restrict__ ws){
  int l=blockIdx.x, c=threadIdx.x;
  __shared__ float Msh[8][8], invMsh[8][8];
  float sl=ws[OFF_S+l];
  float dv=1.f/(sl*tv[c]+SIG2);
  ws[OFF_DVEC+l*128+c]=dv;
  for (int r=0;r<8;r++) ws[OFF_VD+(l*128+c)*8+r]=dv*V[c*8+r];
  __syncthreads();
  if (c<64){
    int r1=c>>3, r2=c&7;
    float a=0.f;
    for (int k=0;k<128;k++) a+=V[k*8+r1]*ws[OFF_VD+(l*128+k)*8+r2];
    Msh[r1][r2]=((r1==r2)?1.f:0.f)+sl*a;
  }
  __syncthreads();
  float accw[8]={0,0,0,0,0,0,0,0};
  for (int k=0;k<128;k++){
    float btck=ws[OFF_BT+c*128+k];
    const float* vdk=ws+OFF_VD+(l*128+k)*8;
    for (int r=0;r<8;r++) accw[r]+=btck*vdk[r];
  }
  for (int r=0;r<8;r++) ws[OFF_W+(l*128+c)*8+r]=accw[r];
  __syncthreads();
  if (c==0){
    float a[8][16];
    for (int i=0;i<8;i++) for (int j=0;j<8;j++){ a[i][j]=Msh[i][j]; a[i][8+j]=(i==j)?1.f:0.f; }
    for (int col=0;col<8;col++){
      int piv=col; float mx=fabsf(a[col][col]);
      for (int r2=col+1;r2<8;r2++){ float v2=fabsf(a[r2][col]); if (v2>mx){mx=v2;piv=r2;} }
      if (piv!=col) for (int j=0;j<16;j++){ float t=a[col][j]; a[col][j]=a[piv][j]; a[piv][j]=t; }
      float dinv=1.f/a[col][col];
      for (int j=0;j<16;j++) a[col][j]*=dinv;
      for (int r2=0;r2<8;r2++) if (r2!=col){
        float fq=a[r2][col];
        for (int j=0;j<16;j++) a[r2][j]-=fq*a[col][j];
      }
    }
    for (int i=0;i<8;i++) for (int j=0;j<8;j++) invMsh[i][j]=a[i][8+j];
  }
  __syncthreads();
  if (c<64) ws[OFF_INVM+l*64+c]=invMsh[c>>3][c&7];
  for (int q=0;q<8;q++){
    float accj=0.f;
    for (int r=0;r<8;r++) accj+=accw[r]*invMsh[r][q];
    ws[OFF_J+(l*128+c)*8+q]=accj;
  }
}

// K3: N_l = Bt diag(d_l) Bt - s_l * J_l W_l^T
__global__ __launch_bounds__(256) void k3_n(float* __restrict__ ws){
  int l=blockIdx.x;
  int idx=blockIdx.y*256+threadIdx.x;
  int c=idx>>7, e=idx&127;
  float sl=ws[OFF_S+l];
  const float* btc=ws+OFF_BT+c*128;
  const float* dv=ws+OFF_DVEC+l*128;
  float acc=0.f;
  for (int k=0;k<128;k++) acc+=btc[k]*dv[k]*ws[OFF_BT+k*128+e];
  float acc2=0.f;
  const float* jc=ws+OFF_J+(l*128+c)*8;
  const float* we=ws+OFF_W+(l*128+e)*8;
  for (int r=0;r<8;r++) acc2+=jc[r]*we[r];
  ws[OFF_N+l*16384+idx]=acc-sl*acc2;
}

// K5: Z[b] = U @ Y[b]   (the reference's row-side application of U)
__global__ __launch_bounds__(256) void k5_z(float* __restrict__ ws){
  int idx=blockIdx.x*256+threadIdx.x;
  int b=idx/3072, r2=idx%3072, l=r2/128, c=r2&127;
  const float* Urow=ws+OFF_U+l*24;
  float acc=0.f;
  for (int k=0;k<24;k++) acc+=Urow[k]*ws[OFF_Y+b*3072+k*128+c];
  ws[OFF_Z+idx]=acc;
}

// K6: H2[b][l][:] = (Z[b][l][:] * (s_l Bt + sig2 I)^{-1}) * Bt  via Woodbury
__global__ __launch_bounds__(128) void k6_h(float* __restrict__ ws){
  int b=blockIdx.x/24, l=blockIdx.x%24, c=threadIdx.x;
  __shared__ float zsh[128], wsh[128], u8[8], y8[8];
  float sl=ws[OFF_S+l];
  zsh[c]=ws[OFF_Z+b*3072+l*128+c];
  __syncthreads();
  if (c<8){ float a=0.f; for (int k=0;k<128;k++) a+=ws[OFF_VD+(l*128+k)*8+c]*zsh[k]; u8[c]=a; }
  __syncthreads();
  if (c<8){ float a=0.f; for (int r=0;r<8;r++) a+=ws[OFF_INVM+l*64+c*8+r]*u8[r]; y8[c]=a; }
  __syncthreads();
  {
    float a=0.f;
    const float* vdc=ws+OFF_VD+(l*128+c)*8;
    for (int r=0;r<8;r++) a+=vdc[r]*y8[r];
    wsh[c]=ws[OFF_DVEC+l*128+c]*zsh[c]-sl*a;
  }
  __syncthreads();
  float acc=0.f;
  for (int k=0;k<128;k++) acc+=wsh[k]*ws[OFF_BT+k*128+c];
  ws[OFF_H2+b*3072+l*128+c]=acc;
}

// K7: mean_final = KU @ H2 + loc_phase^T
__global__ __launch_bounds__(256) void k7_mean(const float* __restrict__ ws, float* __restrict__ out){
  int idx=blockIdx.x*256+threadIdx.x;
  int b=idx/3072, r2=idx%3072, f=r2/128, c=r2&127;
  float acc=0.f;
  for (int l=0;l<24;l++) acc+=ws[OFF_KU+f*24+l]*ws[OFF_H2+b*3072+l*128+c];
  out[idx]=acc+ws[OFF_LOCP+(b*128+c)*24+f];
}

// K8: cov[b, f*128+c, g*128+d] = Kff[f,g]*Bt[c,d] - sum_i KU[f,i]KU[g,i]*N_i[c,d] + sig2*delta
__global__ __launch_bounds__(256) void k8_cov(const float* __restrict__ ws, float* __restrict__ cov){
  int f=blockIdx.x, tile=blockIdx.y, tid=threadIdx.x;
  __shared__ float wfg[576], kffr[24];
  for (int idx=tid; idx<576; idx+=256){
    int g=idx/24, i=idx%24;
    wfg[idx]=ws[OFF_KU+f*24+i]*ws[OFF_KU+g*24+i];
  }
  if (tid<24) kffr[tid]=ws[OFF_KFF+f*24+tid];
  __syncthreads();
  int cd4=tile*256+tid;
  int c=cd4>>5, d0=(cd4&31)*4;
  float4 Nv[24];
  #pragma unroll
  for (int i=0;i<24;i++) Nv[i]=*(const float4*)(ws+OFF_N+i*16384+c*128+d0);
  float4 btv=*(const float4*)(ws+OFF_BT+c*128+d0);
  long rowbase=(long)(f*128+c)*3072;
  for (int g=0;g<24;g++){
    float ax=0.f,ay=0.f,az=0.f,aw=0.f;
    #pragma unroll
    for (int i=0;i<24;i++){
      float w=wfg[g*24+i];
      ax+=w*Nv[i].x; ay+=w*Nv[i].y; az+=w*Nv[i].z; aw+=w*Nv[i].w;
    }
    float kf=kffr[g];
    float4 val;
    val.x=kf*btv.x-ax; val.y=kf*btv.y-ay; val.z=kf*btv.z-az; val.w=kf*btv.w-aw;
    if (g==f && c>=d0 && c<d0+4){
      if (c==d0) val.x+=SIG2; else if (c==d0+1) val.y+=SIG2; else if (c==d0+2) val.z+=SIG2; else val.w+=SIG2;
    }
    long off=rowbase+g*128+d0;
    #pragma unroll
    for (int b=0;b<8;b++){
      *(float4*)(cov+off+(long)b*9437184)=val;
    }
  }
}

extern "C" void kernel_launch(void* const* d_in, const int* in_sizes, int n_in,
                              void* d_out, int out_size, void* d_ws, size_t ws_size,
                              hipStream_t stream){
  (void)in_sizes; (void)n_in; (void)out_size; (void)ws_size;
  const float* x  = (const float*)d_in[0];
  const float* V  = (const float*)d_in[1];
  const float* tv = (const float*)d_in[2];
  float* out = (float*)d_out;
  float* ws  = (float*)d_ws;
  float* cov = out + 24576;

  k1_eigh<<<1,64,0,stream>>>(ws);
  k0_bt<<<64,256,0,stream>>>(V,tv,ws);
  k4_y<<<96,256,0,stream>>>(x,ws);
  k2_wood<<<24,128,0,stream>>>(V,tv,ws);
  k3_n<<<dim3(24,64),256,0,stream>>>(ws);
  k5_z<<<96,256,0,stream>>>(ws);
  k6_h<<<192,128,0,stream>>>(ws);
  k7_mean<<<96,256,0,stream>>>(ws,out);
  k8_cov<<<dim3(24,16),256,0,stream>>>(ws,cov);
}

// Round 3
// 433.137 us; speedup vs baseline: 1.8965x; 1.8965x over previous
//
#include <hip/hip_runtime.h>
#include <math.h>

// Problem constants (fixed by setup_inputs)
#define NB 8
#define NC 128
#define NR 8
#define NT 24
#define SIG2 1.0001f

// workspace layout (float offsets). Total ~2.36 MB.
#define OFF_KFC   0
#define OFF_KFF   576
#define OFF_U     1152
#define OFF_S     1728
#define OFF_KU    1752
#define OFF_BT    2328
#define OFF_DVEC  18712
#define OFF_VD    21784
#define OFF_INVM  46360
#define OFF_W     47896
#define OFF_J     72472
#define OFF_N     97048
#define OFF_Y     490264
#define OFF_Z     514840
#define OFF_H2    539416
#define OFF_LOCP  563992

// ======================= HOST eigensolver =======================
// Faithful port of the device LAPACK path that passed round 1
// (ssytd2 lower + ssteqr 'I' + sorm2r + ascending selection sort).
// Runs on host at capture time; results enter the graph as a by-value
// kernel argument (no memcpy, fully capture-safe, not in timed replay).

static inline float h_fsign(float a, float b){ return copysignf(fabsf(a), b); }

static float h_slapy2(float x, float y){
  float xa=fabsf(x), ya=fabsf(y);
  float w=fmaxf(xa,ya), z=fminf(xa,ya);
  if (z==0.f) return w;
  float t=z/w;
  return w*sqrtf(1.f+t*t);
}

static void h_slartg(float f, float g, float& c, float& s, float& r){
  const float safmin=1.17549435e-38f;
  const float safmax=1.f/1.17549435e-38f;
  float f1=fabsf(f), g1=fabsf(g);
  if (g==0.f){ c=1.f; s=0.f; r=f; }
  else if (f==0.f){ c=0.f; s=copysignf(1.f,g); r=g1; }
  else {
    float rtmin=sqrtf(safmin);
    float rtmax=sqrtf(safmax*0.5f);
    if (f1>rtmin && f1<rtmax && g1>rtmin && g1<rtmax){
      float d=sqrtf(f*f+g*g);
      c=f1/d;
      r=copysignf(d,f);
      s=g/r;
    } else {
      float u=fminf(safmax, fmaxf(safmin, fmaxf(f1,g1)));
      float fs=f/u, gs=g/u;
      float d=sqrtf(fs*fs+gs*gs);
      c=fabsf(fs)/d;
      r=copysignf(d,f);
      s=gs/r;
      r=r*u;
    }
  }
}

static void h_slaev2(float a, float b, float c, float& rt1, float& rt2, float& cs1, float& sn1){
  float sm=a+c, df=a-c, adf=fabsf(df), tb=b+b, ab=fabsf(tb);
  float acmx, acmn;
  if (fabsf(a)>fabsf(c)){acmx=a;acmn=c;} else {acmx=c;acmn=a;}
  float rt;
  if (adf>ab){ float t=ab/adf; rt=adf*sqrtf(1.f+t*t); }
  else if (adf<ab){ float t=adf/ab; rt=ab*sqrtf(1.f+t*t); }
  else rt=ab*sqrtf(2.f);
  int sgn1;
  if (sm<0.f){ rt1=0.5f*(sm-rt); sgn1=-1; rt2=(acmx/rt1)*acmn-(b/rt1)*b; }
  else if (sm>0.f){ rt1=0.5f*(sm+rt); sgn1=1; rt2=(acmx/rt1)*acmn-(b/rt1)*b; }
  else { rt1=0.5f*rt; rt2=-0.5f*rt; sgn1=1; }
  float cs; int sgn2;
  if (df>=0.f){ cs=df+rt; sgn2=1; } else { cs=df-rt; sgn2=-1; }
  float acs=fabsf(cs);
  if (acs>ab){ float ct=-tb/cs; sn1=1.f/sqrtf(1.f+ct*ct); cs1=ct*sn1; }
  else {
    if (ab==0.f){ cs1=1.f; sn1=0.f; }
    else { float tn=-cs/tb; cs1=1.f/sqrtf(1.f+tn*tn); sn1=tn*cs1; }
  }
  if (sgn1==sgn2){ float tn=cs1; cs1=-sn1; sn1=tn; }
}

static void host_eigh(float* Uout /*576*/, float* Sout /*24*/){
  float A[24][24], Z[24][24], dd[24], ee[24], tauv[24], wcA[24], wsA[24];
  const float h = (float)(3.14159265358979323846/24.0);
  for (int i=0;i<24;i++) for (int j=0;j<24;j++){
    float ti=(float)i*h, tj=(float)j*h;
    A[i][j]=expf(-fabsf(ti-tj));
  }
  // ---------- ssytd2 (lower) ----------
  for (int i0=0;i0<23;i0++){
    float alpha=A[i0+1][i0];
    float scale=0.f, ssq=1.f;
    for (int r=i0+2;r<24;r++){
      float ax=fabsf(A[r][i0]);
      if (ax!=0.f){
        if (scale<ax){ float t=scale/ax; ssq=1.f+ssq*t*t; scale=ax; }
        else { float t=ax/scale; ssq+=t*t; }
      }
    }
    float xnorm=scale*sqrtf(ssq);
    float taui, beta;
    if (xnorm==0.f){ taui=0.f; beta=alpha; }
    else {
      beta=-h_fsign(h_slapy2(alpha,xnorm), alpha);
      taui=(beta-alpha)/beta;
      float sc=1.f/(alpha-beta);
      for (int r=i0+2;r<24;r++) A[r][i0]*=sc;
    }
    ee[i0]=beta; tauv[i0]=taui;
    A[i0+1][i0]=1.f;
    if (taui!=0.f){
      int m=23-i0;
      float w[24];
      for (int jj=0;jj<m;jj++){
        int j=i0+1+jj;
        float acc=0.f;
        for (int k=i0+1;k<=j;k++) acc+=A[j][k]*A[k][i0];
        for (int k=j+1;k<24;k++)  acc+=A[k][j]*A[k][i0];
        w[jj]=taui*acc;
      }
      float dt=0.f;
      for (int r=0;r<m;r++) dt+=w[r]*A[i0+1+r][i0];
      float al=-0.5f*taui*dt;
      for (int r=0;r<m;r++) w[r]+=al*A[i0+1+r][i0];
      for (int jj=0;jj<m;jj++){
        int j=i0+1+jj;
        float vj=A[j][i0], wj=w[jj];
        for (int k=i0+1;k<=j;k++) A[j][k]-=vj*w[k-(i0+1)]+wj*A[k][i0];
      }
    }
    A[i0+1][i0]=ee[i0]; dd[i0]=A[i0][i0];
  }
  dd[23]=A[23][23];
  for (int i=0;i<24;i++) for (int j=0;j<24;j++) Z[i][j]=(i==j)?1.f:0.f;
  // ---------- ssteqr('I') ----------
  const float LEPS=5.9604645e-08f, EPS2=LEPS*LEPS, SAFMIN=1.17549435e-38f;
  const float SSFMAX=sqrtf(1.f/SAFMIN)/3.f, SSFMIN=sqrtf(SAFMIN)/EPS2;
  const int NMAXIT=720;
  #define D1(i) dd[(i)-1]
  #define E1(i) ee[(i)-1]
  #define WC1(i) wcA[(i)-1]
  #define WS1(i) wsA[(i)-1]
  int l=1,lend=1,lsv=1,lendsv=1,l1=1,jtot=0,iscale=0;
  float anorm=0.f;
  int phase=0;
  for (int guard=0; guard<200000; ++guard){
    if (phase==4) break;
    if (phase==0){
      if (l1>24){ phase=4; continue; }
      if (l1>1) E1(l1-1)=0.f;
      int m=24;
      for (int mm=l1; mm<=23; mm++){
        float tst=fabsf(E1(mm));
        if (tst==0.f){ m=mm; break; }
        if (tst<=(sqrtf(fabsf(D1(mm)))*sqrtf(fabsf(D1(mm+1))))*LEPS){ E1(mm)=0.f; m=mm; break; }
      }
      l=l1; lsv=l; lend=m; lendsv=m; l1=m+1;
      if (lend==l) continue;
      anorm=0.f;
      for (int i=l;i<=lend;i++) anorm=fmaxf(anorm,fabsf(D1(i)));
      for (int i=l;i<=lend-1;i++) anorm=fmaxf(anorm,fabsf(E1(i)));
      iscale=0;
      if (anorm==0.f) continue;
      if (anorm>SSFMAX){ iscale=1; float sc=SSFMAX/anorm; for (int i=l;i<=lend;i++) D1(i)*=sc; for (int i=l;i<lend;i++) E1(i)*=sc; }
      else if (anorm<SSFMIN){ iscale=2; float sc=SSFMIN/anorm; for (int i=l;i<=lend;i++) D1(i)*=sc; for (int i=l;i<lend;i++) E1(i)*=sc; }
      if (fabsf(D1(lend))<fabsf(D1(l))){ lend=lsv; l=lendsv; }
      phase=(lend>l)?1:2;
      continue;
    }
    if (phase==1){ // QL
      int m=lend;
      if (l!=lend){
        for (int mm=l;mm<=lend-1;mm++){
          float tst=fabsf(E1(mm)); tst*=tst;
          if (tst<=(EPS2*fabsf(D1(mm)))*fabsf(D1(mm+1))+SAFMIN){ m=mm; break; }
        }
      }
      if (m<lend) E1(m)=0.f;
      float p=D1(l);
      if (m==l){ D1(l)=p; l=l+1; if (l>lend) phase=3; continue; }
      if (m==l+1){
        float rt1,rt2,cc,ssv;
        h_slaev2(D1(l),E1(l),D1(l+1),rt1,rt2,cc,ssv);
        WC1(l)=cc; WS1(l)=ssv;
        D1(l)=rt1; D1(l+1)=rt2; E1(l)=0.f;
        for (int j=l;j>=l;j--){
          float ct=WC1(j), stv=WS1(j);
          if (ct!=1.f || stv!=0.f)
            for (int r=0;r<24;r++){ float zb=Z[r][j], za=Z[r][j-1]; Z[r][j]=ct*zb-stv*za; Z[r][j-1]=stv*zb+ct*za; }
        }
        l=l+2;
        if (l>lend) phase=3;
        continue;
      }
      if (jtot==NMAXIT){ phase=3; continue; }
      jtot++;
      float g=(D1(l+1)-p)/(2.f*E1(l));
      float r=h_slapy2(g,1.f);
      g=D1(m)-p+(E1(l)/(g+h_fsign(r,g)));
      float sv=1.f, cv=1.f;
      p=0.f;
      for (int i=m-1;i>=l;i--){
        float fv=sv*E1(i), bv=cv*E1(i);
        h_slartg(g,fv,cv,sv,r);
        if (i!=m-1) E1(i+1)=r;
        g=D1(i+1)-p;
        r=(D1(i)-g)*sv+2.f*cv*bv;
        p=sv*r;
        D1(i+1)=g+p;
        g=cv*r-bv;
        WC1(i)=cv; WS1(i)=-sv;
      }
      D1(l)=D1(l)-p;
      E1(l)=g;
      for (int j=m-1;j>=l;j--){
        float ct=WC1(j), stv=WS1(j);
        if (ct!=1.f || stv!=0.f)
          for (int r=0;r<24;r++){ float zb=Z[r][j], za=Z[r][j-1]; Z[r][j]=ct*zb-stv*za; Z[r][j-1]=stv*zb+ct*za; }
      }
      continue;
    }
    if (phase==2){ // QR
      int m=lend;
      if (l!=lend){
        for (int mm=l;mm>=lend+1;mm--){
          float tst=fabsf(E1(mm-1)); tst*=tst;
          if (tst<=(EPS2*fabsf(D1(mm)))*fabsf(D1(mm-1))+SAFMIN){ m=mm; break; }
        }
      }
      if (m>lend) E1(m-1)=0.f;
      float p=D1(l);
      if (m==l){ D1(l)=p; l=l-1; if (l<lend) phase=3; continue; }
      if (m==l-1){
        float rt1,rt2,cc,ssv;
        h_slaev2(D1(l-1),E1(l-1),D1(l),rt1,rt2,cc,ssv);
        WC1(m)=cc; WS1(m)=ssv;
        D1(l-1)=rt1; D1(l)=rt2; E1(l-1)=0.f;
        for (int j=m;j<=m;j++){
          float ct=WC1(j), stv=WS1(j);
          if (ct!=1.f || stv!=0.f)
            for (int r=0;r<24;r++){ float zb=Z[r][j], za=Z[r][j-1]; Z[r][j]=ct*zb-stv*za; Z[r][j-1]=stv*zb+ct*za; }
        }
        l=l-2;
        if (l<lend) phase=3;
        continue;
      }
      if (jtot==NMAXIT){ phase=3; continue; }
      jtot++;
      float g=(D1(l-1)-p)/(2.f*E1(l-1));
      float r=h_slapy2(g,1.f);
      g=D1(m)-p+(E1(l-1)/(g+h_fsign(r,g)));
      float sv=1.f, cv=1.f;
      p=0.f;
      for (int i=m;i<=l-1;i++){
        float fv=sv*E1(i), bv=cv*E1(i);
        h_slartg(g,fv,cv,sv,r);
        if (i!=m) E1(i-1)=r;
        g=D1(i)-p;
        r=(D1(i+1)-g)*sv+2.f*cv*bv;
        p=sv*r;
        D1(i)=g+p;
        g=cv*r-bv;
        WC1(i)=cv; WS1(i)=sv;
      }
      D1(l)=D1(l)-p;
      E1(l-1)=g;
      for (int j=m;j<=l-1;j++){
        float ct=WC1(j), stv=WS1(j);
        if (ct!=1.f || stv!=0.f)
          for (int r=0;r<24;r++){ float zb=Z[r][j], za=Z[r][j-1]; Z[r][j]=ct*zb-stv*za; Z[r][j-1]=stv*zb+ct*za; }
      }
      continue;
    }
    if (phase==3){
      if (iscale==1){ float sc=anorm/SSFMAX; for (int i=lsv;i<=lendsv;i++) D1(i)*=sc; for (int i=lsv;i<lendsv;i++) E1(i)*=sc; }
      else if (iscale==2){ float sc=anorm/SSFMIN; for (int i=lsv;i<=lendsv;i++) D1(i)*=sc; for (int i=lsv;i<lendsv;i++) E1(i)*=sc; }
      phase=(jtot<NMAXIT)?0:4;
      continue;
    }
  }
  // ---------- ascending selection sort with column swaps ----------
  for (int ii=2; ii<=24; ii++){
    int i=ii-1, k=i; float p=D1(i);
    for (int jq=ii;jq<=24;jq++) if (D1(jq)<p){ k=jq; p=D1(jq); }
    if (k!=i){
      D1(k)=D1(i); D1(i)=p;
      for (int r=0;r<24;r++){ float t=Z[r][i-1]; Z[r][i-1]=Z[r][k-1]; Z[r][k-1]=t; }
    }
  }
  #undef D1
  #undef E1
  #undef WC1
  #undef WS1
  // ---------- sorm2r: evec = Q * Z ----------
  for (int jc=0;jc<24;jc++){
    for (int i0=22;i0>=0;i0--){
      float taui=tauv[i0];
      if (taui!=0.f){
        float wv=Z[i0+1][jc];
        for (int r=i0+2;r<24;r++) wv+=A[r][i0]*Z[r][jc];
        Z[i0+1][jc]-=taui*wv;
        for (int r=i0+2;r<24;r++) Z[r][jc]-=taui*A[r][i0]*wv;
      }
    }
  }
  for (int i=0;i<24;i++) for (int j=0;j<24;j++) Uout[i*24+j]=Z[i][j];
  for (int i=0;i<24;i++) Sout[i]=dd[i];
}

// ======================= DEVICE kernels =======================

struct EigPack { float u[576]; float s[24]; };

// K1b: unpack host eigendecomposition (by-value kernarg), compute KFC/KFF/KU.
__global__ __launch_bounds__(256) void k1b_const(EigPack p, float* __restrict__ ws){
  int tid=threadIdx.x;
  __shared__ float Ush[24][24], Kfsh[24][24];
  const float h = (float)(3.14159265358979323846/24.0);
  for (int idx=tid; idx<576; idx+=256){
    int i=idx/24, j=idx%24;
    float u=p.u[idx];
    Ush[i][j]=u;
    ws[OFF_U+idx]=u;
    float tf=(float)(24+i)*h, tj=(float)j*h, tg=(float)(24+j)*h;
    float kfc=expf(-fabsf(tf-tj));
    Kfsh[i][j]=kfc;
    ws[OFF_KFC+idx]=kfc;
    ws[OFF_KFF+idx]=expf(-fabsf(tf-tg));
  }
  if (tid<24) ws[OFF_S+tid]=p.s[tid];
  __syncthreads();
  for (int idx=tid; idx<576; idx+=256){
    int f=idx/24, lq=idx%24;
    float acc=0.f;
    for (int i=0;i<24;i++) acc+=Kfsh[f][i]*Ush[i][lq];
    ws[OFF_KU+idx]=acc;
  }
}

// K0: Bt = V V^T + diag(tv)
__global__ __launch_bounds__(256) void k0_bt(const float* __restrict__ V, const float* __restrict__ tv, float* __restrict__ ws){
  int idx=blockIdx.x*256+threadIdx.x;
  int c=idx>>7, d=idx&127;
  float acc=0.f;
  for (int r=0;r<8;r++) acc+=V[c*8+r]*V[d*8+r];
  if (c==d) acc+=tv[c];
  ws[OFF_BT+idx]=acc;
}

// K4: Y[b][l][c] and loc_phase[b][c][f]
__global__ __launch_bounds__(256) void k4_y(const float* __restrict__ x, float* __restrict__ ws){
  int idx=blockIdx.x*256+threadIdx.x; // 24576
  int b=idx/3072, r2=idx%3072, i=r2/128, j=r2&127;
  const float* xb=x+(size_t)(b*128+j)*48;
  ws[OFF_Y + b*3072 + i*128 + j] = xb[24+i]-0.5f*(xb[12+(i>>1)]+xb[36+(i>>1)]);
  ws[OFF_LOCP + (b*128+j)*24 + i] = 0.5f*(xb[i]+xb[24+i]);
}

// K2: per time-mode Woodbury factors: dvec, Vd, invM, W=Bt*Vd, J=W*invM
__global__ __launch_bounds__(128) void k2_wood(const float* __restrict__ V, const float* __restrict__ tv, float* __restrict__ ws){
  int l=blockIdx.x, c=threadIdx.x;
  __shared__ float Msh[8][8], invMsh[8][8];
  float sl=ws[OFF_S+l];
  float dv=1.f/(sl*tv[c]+SIG2);
  ws[OFF_DVEC+l*128+c]=dv;
  for (int r=0;r<8;r++) ws[OFF_VD+(l*128+c)*8+r]=dv*V[c*8+r];
  __syncthreads();
  if (c<64){
    int r1=c>>3, r2=c&7;
    float a=0.f;
    for (int k=0;k<128;k++) a+=V[k*8+r1]*ws[OFF_VD+(l*128+k)*8+r2];
    Msh[r1][r2]=((r1==r2)?1.f:0.f)+sl*a;
  }
  __syncthreads();
  float accw[8]={0,0,0,0,0,0,0,0};
  for (int k=0;k<128;k++){
    float btck=ws[OFF_BT+c*128+k];
    const float* vdk=ws+OFF_VD+(l*128+k)*8;
    for (int r=0;r<8;r++) accw[r]+=btck*vdk[r];
  }
  for (int r=0;r<8;r++) ws[OFF_W+(l*128+c)*8+r]=accw[r];
  __syncthreads();
  if (c==0){
    float a[8][16];
    for (int i=0;i<8;i++) for (int j=0;j<8;j++){ a[i][j]=Msh[i][j]; a[i][8+j]=(i==j)?1.f:0.f; }
    for (int col=0;col<8;col++){
      int piv=col; float mx=fabsf(a[col][col]);
      for (int r2=col+1;r2<8;r2++){ float v2=fabsf(a[r2][col]); if (v2>mx){mx=v2;piv=r2;} }
      if (piv!=col) for (int j=0;j<16;j++){ float t=a[col][j]; a[col][j]=a[piv][j]; a[piv][j]=t; }
      float dinv=1.f/a[col][col];
      for (int j=0;j<16;j++) a[col][j]*=dinv;
      for (int r2=0;r2<8;r2++) if (r2!=col){
        float fq=a[r2][col];
        for (int j=0;j<16;j++) a[r2][j]-=fq*a[col][j];
      }
    }
    for (int i=0;i<8;i++) for (int j=0;j<8;j++) invMsh[i][j]=a[i][8+j];
  }
  __syncthreads();
  if (c<64) ws[OFF_INVM+l*64+c]=invMsh[c>>3][c&7];
  for (int q=0;q<8;q++){
    float accj=0.f;
    for (int r=0;r<8;r++) accj+=accw[r]*invMsh[r][q];
    ws[OFF_J+(l*128+c)*8+q]=accj;
  }
}

// K3: N_l = Bt diag(d_l) Bt - s_l * J_l W_l^T
__global__ __launch_bounds__(256) void k3_n(float* __restrict__ ws){
  int l=blockIdx.x;
  int idx=blockIdx.y*256+threadIdx.x;
  int c=idx>>7, e=idx&127;
  float sl=ws[OFF_S+l];
  const float* btc=ws+OFF_BT+c*128;
  const float* dv=ws+OFF_DVEC+l*128;
  float acc=0.f;
  for (int k=0;k<128;k++) acc+=btc[k]*dv[k]*ws[OFF_BT+k*128+e];
  float acc2=0.f;
  const float* jc=ws+OFF_J+(l*128+c)*8;
  const float* we=ws+OFF_W+(l*128+e)*8;
  for (int r=0;r<8;r++) acc2+=jc[r]*we[r];
  ws[OFF_N+l*16384+idx]=acc-sl*acc2;
}

// K5: Z[b] = U @ Y[b]
__global__ __launch_bounds__(256) void k5_z(float* __restrict__ ws){
  int idx=blockIdx.x*256+threadIdx.x;
  int b=idx/3072, r2=idx%3072, l=r2/128, c=r2&127;
  const float* Urow=ws+OFF_U+l*24;
  float acc=0.f;
  for (int k=0;k<24;k++) acc+=Urow[k]*ws[OFF_Y+b*3072+k*128+c];
  ws[OFF_Z+idx]=acc;
}

// K6: H2[b][l][:] = (Z[b][l][:] * (s_l Bt + sig2 I)^{-1}) * Bt  via Woodbury
__global__ __launch_bounds__(128) void k6_h(float* __restrict__ ws){
  int b=blockIdx.x/24, l=blockIdx.x%24, c=threadIdx.x;
  __shared__ float zsh[128], wsh[128], u8[8], y8[8];
  float sl=ws[OFF_S+l];
  zsh[c]=ws[OFF_Z+b*3072+l*128+c];
  __syncthreads();
  if (c<8){ float a=0.f; for (int k=0;k<128;k++) a+=ws[OFF_VD+(l*128+k)*8+c]*zsh[k]; u8[c]=a; }
  __syncthreads();
  if (c<8){ float a=0.f; for (int r=0;r<8;r++) a+=ws[OFF_INVM+l*64+c*8+r]*u8[r]; y8[c]=a; }
  __syncthreads();
  {
    float a=0.f;
    const float* vdc=ws+OFF_VD+(l*128+c)*8;
    for (int r=0;r<8;r++) a+=vdc[r]*y8[r];
    wsh[c]=ws[OFF_DVEC+l*128+c]*zsh[c]-sl*a;
  }
  __syncthreads();
  float acc=0.f;
  for (int k=0;k<128;k++) acc+=wsh[k]*ws[OFF_BT+k*128+c];
  ws[OFF_H2+b*3072+l*128+c]=acc;
}

// K7: mean_final = KU @ H2 + loc_phase^T
__global__ __launch_bounds__(256) void k7_mean(const float* __restrict__ ws, float* __restrict__ out){
  int idx=blockIdx.x*256+threadIdx.x;
  int b=idx/3072, r2=idx%3072, f=r2/128, c=r2&127;
  float acc=0.f;
  for (int l=0;l<24;l++) acc+=ws[OFF_KU+f*24+l]*ws[OFF_H2+b*3072+l*128+c];
  out[idx]=acc+ws[OFF_LOCP+(b*128+c)*24+f];
}

// K8: cov[b, f*128+c, g*128+d] = Kff[f,g]*Bt[c,d] - sum_i KU[f,i]KU[g,i]*N_i[c,d] + sig2*delta
__global__ __launch_bounds__(256) void k8_cov(const float* __restrict__ ws, float* __restrict__ cov){
  int f=blockIdx.x, tile=blockIdx.y, tid=threadIdx.x;
  __shared__ float wfg[576], kffr[24];
  for (int idx=tid; idx<576; idx+=256){
    int g=idx/24, i=idx%24;
    wfg[idx]=ws[OFF_KU+f*24+i]*ws[OFF_KU+g*24+i];
  }
  if (tid<24) kffr[tid]=ws[OFF_KFF+f*24+tid];
  __syncthreads();
  int cd4=tile*256+tid;
  int c=cd4>>5, d0=(cd4&31)*4;
  float4 Nv[24];
  #pragma unroll
  for (int i=0;i<24;i++) Nv[i]=*(const float4*)(ws+OFF_N+i*16384+c*128+d0);
  float4 btv=*(const float4*)(ws+OFF_BT+c*128+d0);
  long rowbase=(long)(f*128+c)*3072;
  for (int g=0;g<24;g++){
    float ax=0.f,ay=0.f,az=0.f,aw=0.f;
    #pragma unroll
    for (int i=0;i<24;i++){
      float w=wfg[g*24+i];
      ax+=w*Nv[i].x; ay+=w*Nv[i].y; az+=w*Nv[i].z; aw+=w*Nv[i].w;
    }
    float kf=kffr[g];
    float4 val;
    val.x=kf*btv.x-ax; val.y=kf*btv.y-ay; val.z=kf*btv.z-az; val.w=kf*btv.w-aw;
    if (g==f && c>=d0 && c<d0+4){
      if (c==d0) val.x+=SIG2; else if (c==d0+1) val.y+=SIG2; else if (c==d0+2) val.z+=SIG2; else val.w+=SIG2;
    }
    long off=rowbase+g*128+d0;
    #pragma unroll
    for (int b=0;b<8;b++){
      *(float4*)(cov+off+(long)b*9437184)=val;
    }
  }
}

extern "C" void kernel_launch(void* const* d_in, const int* in_sizes, int n_in,
                              void* d_out, int out_size, void* d_ws, size_t ws_size,
                              hipStream_t stream){
  (void)in_sizes; (void)n_in; (void)out_size; (void)ws_size;
  const float* x  = (const float*)d_in[0];
  const float* V  = (const float*)d_in[1];
  const float* tv = (const float*)d_in[2];
  float* out = (float*)d_out;
  float* ws  = (float*)d_ws;
  float* cov = out + 24576;

  // Host eigendecomposition of the CONSTANT Kc (runs at capture time only;
  // deterministic, identical every call). Values enter the graph as a
  // by-value kernel argument — no memcpy, capture-safe.
  EigPack pack;
  host_eigh(pack.u, pack.s);

  k1b_const<<<1,256,0,stream>>>(pack,ws);
  k0_bt<<<64,256,0,stream>>>(V,tv,ws);
  k4_y<<<96,256,0,stream>>>(x,ws);
  k2_wood<<<24,128,0,stream>>>(V,tv,ws);
  k3_n<<<dim3(24,64),256,0,stream>>>(ws);
  k5_z<<<96,256,0,stream>>>(ws);
  k6_h<<<192,128,0,stream>>>(ws);
  k7_mean<<<96,256,0,stream>>>(ws,out);
  k8_cov<<<dim3(24,16),256,0,stream>>>(ws,cov);
}